// Round 5
// baseline (143.359 us; speedup 1.0000x reference)
//
#include <hip/hip_runtime.h>
#include <cstdint>
#include <cstddef>

#define S_LEN 2048
#define DMODEL 1024
#define NHEADS 16
#define DKH 64
#define MROWS 4096
#define BH_CNT 32

typedef __bf16 bf16x8 __attribute__((ext_vector_type(8)));
typedef __bf16 bf16x2 __attribute__((ext_vector_type(2)));
typedef float f32x4 __attribute__((ext_vector_type(4)));
typedef unsigned int u32x4 __attribute__((ext_vector_type(4)));
typedef unsigned int u32;
typedef unsigned short u16;

__device__ __forceinline__ u16 f2bfu(float f) {
  u32 u = __float_as_uint(f);
  return (u16)((u + 0x7FFFu + ((u >> 16) & 1u)) >> 16);
}

// compiler-cast bf16 pack (lowers to v_cvt_pk_bf16_f32 on gfx950)
__device__ __forceinline__ u32 pk_bf16(float a, float b) {
  bf16x2 v;
  v[0] = (__bf16)a;
  v[1] = (__bf16)b;
  return __builtin_bit_cast(u32, v);
}

// true-swap cross-lane ops (gfx950): both operands modified
__device__ __forceinline__ void pl32swap(u32& a, u32& b) {
#if __has_builtin(__builtin_amdgcn_permlane32_swap)
  auto r = __builtin_amdgcn_permlane32_swap((int)a, (int)b, false, false);
  a = (u32)r[0]; b = (u32)r[1];
#else
  asm volatile("v_permlane32_swap_b32 %0, %1" : "+v"(a), "+v"(b));
#endif
}
__device__ __forceinline__ void pl16swap(u32& a, u32& b) {
#if __has_builtin(__builtin_amdgcn_permlane16_swap)
  auto r = __builtin_amdgcn_permlane16_swap((int)a, (int)b, false, false);
  a = (u32)r[0]; b = (u32)r[1];
#else
  asm volatile("v_permlane16_swap_b32 %0, %1" : "+v"(a), "+v"(b));
#endif
}

__device__ __forceinline__ void gload16(void* lds, const void* g) {
  __builtin_amdgcn_global_load_lds(
      (const __attribute__((address_space(1))) void*)g,
      (__attribute__((address_space(3))) void*)lds, 16, 0, 0);
}

// ---------------- prep: x -> bf16 ----------------
__global__ __launch_bounds__(256) void prep_xb_k(const float* __restrict__ x,
                                                 u16* __restrict__ xb) {
  int i = (blockIdx.x * 256 + threadIdx.x) * 4;
  float4 v = *(const float4*)(x + i);
  *(uint2*)(xb + i) = make_uint2(pk_bf16(v.x, v.y), pk_bf16(v.z, v.w));
}

// ---------------- prep: W^T (n-major) bf16, K pre-scaled ----------------
// K scale folds 1/sqrt(dk)*phase AND 1/(2pi): scores arrive in REVOLUTIONS,
// so attention uses raw v_cos (no range-reduce mul).
__global__ __launch_bounds__(256) void prep_w_k(const float* __restrict__ Wq,
    const float* __restrict__ Wk, const float* __restrict__ Wv,
    const float* __restrict__ ps, u16* __restrict__ Wb) {
  __shared__ float tile[32][33];
  int sel = blockIdx.z;
  const float* W = sel == 0 ? Wq : (sel == 1 ? Wk : Wv);
  int k0 = blockIdx.x * 32, c0 = blockIdx.y * 32;
  int tx = threadIdx.x, ty = threadIdx.y;
#pragma unroll
  for (int i = 0; i < 4; ++i)
    tile[ty + i * 8][tx] = W[(size_t)(k0 + ty + i * 8) * DMODEL + c0 + tx];
  __syncthreads();
#pragma unroll
  for (int i = 0; i < 4; ++i) {
    int row = ty + i * 8;
    float v = tile[tx][row];
    if (sel == 1) v *= 0.019894367886486918f * ps[(c0 + row) >> 6];  // 0.125/(2pi)
    Wb[(size_t)(sel * 1024 + c0 + row) * DMODEL + k0 + tx] = f2bfu(v);
  }
}

// ---------------- prep: Wo_eff[d][j] = sum_m (sum_h ent[h][m]) * Wo[m*64+d][j] ----------------
__global__ __launch_bounds__(256) void prep_woeff_k(const float* __restrict__ Wo,
    const float* __restrict__ ent, float* __restrict__ Woeff) {
  __shared__ float e[16];
  int t = threadIdx.x;
  if (t < 16) {
    float s = 0.f;
#pragma unroll
    for (int h = 0; h < 16; ++h) s += ent[h * 16 + t];
    e[t] = s;
  }
  __syncthreads();
  int gid = blockIdx.x * 256 + t;
  int d = gid >> 10, j = gid & 1023;
  float acc = 0.f;
#pragma unroll
  for (int m = 0; m < 16; ++m) acc += e[m] * Wo[(size_t)((m << 6) + d) * DMODEL + j];
  Woeff[(size_t)d * DMODEL + j] = acc;
}

// ---------------- QKV projection GEMM: [4096,1024] x [1024,3072] ----------------
// 128x128 tile, BK=32, double-buffered staging, one barrier per K-step.
// Epilogue: C-tile staged through LDS (XOR-swizzled) -> fully coalesced
// 128B-run global stores (incl. the V transpose).
__global__ __launch_bounds__(256) void gemm_qkv_k(const u16* __restrict__ xb,
    const u16* __restrict__ Wb, u16* __restrict__ Qb, u16* __restrict__ Kb,
    u16* __restrict__ Vt) {
  __shared__ __align__(16) u16 SMEM[2][2][128 * 32];  // [A/B][dbuf][tile]
  int tid = threadIdx.x;
  int lane = tid & 63, w = tid >> 6;
  int c = lane & 15, g = lane >> 4;
  int wr = w >> 1, wc = w & 1;
  int m0 = blockIdx.x * 128, n0 = blockIdx.y * 128;

  int cij0 = (w * 2) * 64 + lane, cij1 = (w * 2 + 1) * 64 + lane;
  int row0 = cij0 >> 2, kp0 = (cij0 & 3) ^ (row0 & 3);
  int row1 = cij1 >> 2, kp1 = (cij1 & 3) ^ (row1 & 3);
  const u16* a0p = xb + (size_t)(m0 + row0) * DMODEL + kp0 * 8;
  const u16* a1p = xb + (size_t)(m0 + row1) * DMODEL + kp1 * 8;
  const u16* b0p = Wb + (size_t)(n0 + row0) * DMODEL + kp0 * 8;
  const u16* b1p = Wb + (size_t)(n0 + row1) * DMODEL + kp1 * 8;

  f32x4 acc[4][4];
#pragma unroll
  for (int i = 0; i < 4; ++i)
#pragma unroll
    for (int j = 0; j < 4; ++j) acc[i][j] = (f32x4){0.f, 0.f, 0.f, 0.f};

  // prologue stage
  gload16(&SMEM[0][0][(w * 2) * 512], a0p);
  gload16(&SMEM[0][0][(w * 2 + 1) * 512], a1p);
  gload16(&SMEM[1][0][(w * 2) * 512], b0p);
  gload16(&SMEM[1][0][(w * 2 + 1) * 512], b1p);
  __syncthreads();

  int cur = 0;
  for (int kt = 0; kt < DMODEL; kt += 32) {
    if (kt + 32 < DMODEL) {
      int nx = cur ^ 1, ko = kt + 32;
      gload16(&SMEM[0][nx][(w * 2) * 512], a0p + ko);
      gload16(&SMEM[0][nx][(w * 2 + 1) * 512], a1p + ko);
      gload16(&SMEM[1][nx][(w * 2) * 512], b0p + ko);
      gload16(&SMEM[1][nx][(w * 2 + 1) * 512], b1p + ko);
    }
    const u16* Ac = SMEM[0][cur];
    const u16* Bc = SMEM[1][cur];
    bf16x8 af[4], bf[4];
#pragma unroll
    for (int i = 0; i < 4; ++i) {
      int ra = wr * 64 + i * 16 + c;
      af[i] = *(const bf16x8*)(Ac + ra * 32 + ((g ^ (ra & 3)) * 8));
      int rb = wc * 64 + i * 16 + c;
      bf[i] = *(const bf16x8*)(Bc + rb * 32 + ((g ^ (rb & 3)) * 8));
    }
#pragma unroll
    for (int i = 0; i < 4; ++i)
#pragma unroll
      for (int j = 0; j < 4; ++j)
        acc[i][j] = __builtin_amdgcn_mfma_f32_16x16x32_bf16(af[i], bf[j], acc[i][j], 0, 0, 0);
    __syncthreads();
    cur ^= 1;
  }

  // ---- epilogue via LDS (reuse staging buffers: 32KB = 128x128 u16) ----
  int sel = n0 >> 10;
  char* Ls = (char*)&SMEM[0][0][0];
  if (sel == 2) {
    // LDS layout transposed: row = n-local (d), col = m-local (s)
#pragma unroll
    for (int i = 0; i < 4; ++i)
#pragma unroll
      for (int jf = 0; jf < 4; ++jf) {
        int n = wc * 64 + jf * 16 + c;
        int m = wr * 64 + i * 16 + 4 * g;
        int byte = n * 256 + ((m * 2) ^ ((n & 7) << 4));
        *(uint2*)(Ls + byte) = make_uint2(pk_bf16(acc[i][jf][0], acc[i][jf][1]),
                                          pk_bf16(acc[i][jf][2], acc[i][jf][3]));
      }
  } else {
    // LDS layout: row = m-local (s), col = n-local (d)
#pragma unroll
    for (int i = 0; i < 4; ++i)
#pragma unroll
      for (int jf = 0; jf < 4; ++jf) {
        int n = wc * 64 + jf * 16 + c;
#pragma unroll
        for (int j = 0; j < 4; ++j) {
          int m = wr * 64 + i * 16 + 4 * g + j;
          int byte = m * 256 + ((n * 2) ^ ((m & 7) << 4));
          __bf16 hv = (__bf16)acc[i][jf][j];
          *(u16*)(Ls + byte) = __builtin_bit_cast(u16, hv);
        }
      }
  }
  __syncthreads();
  int r = tid >> 1, half = tid & 1;
  int h0 = (n0 & 1023) >> 6;
  int b = m0 >> 11, sbase = m0 & 2047;
  u16* dst;
  if (sel == 2) {
    int bh = b * 16 + h0 + (r >> 6), d = r & 63;
    dst = Vt + ((size_t)bh * DKH + d) * S_LEN + sbase + half * 64;
  } else {
    u16* base = (sel == 0 ? Qb : Kb);
    int bh = b * 16 + h0 + half;
    dst = base + ((size_t)bh * S_LEN + sbase + r) * DKH;
  }
#pragma unroll
  for (int kk = 0; kk < 8; ++kk) {
    int byte = r * 256 + ((half * 128 + kk * 16) ^ ((r & 7) << 4));
    *(uint4*)(dst + kk * 8) = *(const uint4*)(Ls + byte);
  }
}

// ---------------- fused cos-softmax flash attention ----------------
// 2x2 wave split: wave w -> (h = k-half of tile, qh = q-half of block).
// Each wave: S^T = mfma(K[h-slice], Q[qh]) -> in-register softmax ->
// permlane32/16 swaps redistribute P into the PV B-fragment (NO LDS P) ->
// PV accumulates att^T partials over the wave's k subset. Epilogue combines
// h-partners through retired K/V LDS. KBLK=64, dbuf, XCD-swizzled grid.
__global__ __launch_bounds__(256) void attn_k(const u16* __restrict__ Qb,
    const u16* __restrict__ Kb, const u16* __restrict__ Vt,
    float* __restrict__ attbuf) {
  __shared__ __align__(16) u16 Ks[2][64 * 64];
  __shared__ __align__(16) u16 Vs[2][64 * 64];
  __shared__ float dred[4][2][16];
  int fid = blockIdx.x;
  int swz = (fid & 7) * 128 + (fid >> 3);  // 1024 blocks, 8 XCDs -> bijective
  int bh = swz >> 5, qblk = swz & 31;
  int tid = threadIdx.x;
  int lane = tid & 63, w = tid >> 6;
  int c = lane & 15, g = lane >> 4;
  int h = w >> 1, qh = w & 1;
  int q0 = qblk * 64;
  const u16* Kbase = Kb + (size_t)bh * S_LEN * DKH;
  const u16* Vbase = Vt + (size_t)bh * DKH * S_LEN;

  int cij0 = (w * 2) * 64 + lane, cij1 = (w * 2 + 1) * 64 + lane;
  int srow0 = cij0 >> 3, skp0 = (cij0 & 7) ^ (srow0 & 7);
  int srow1 = cij1 >> 3, skp1 = (cij1 & 7) ^ (srow1 & 7);
  const u16* k0p = Kbase + (size_t)srow0 * DKH + skp0 * 8;
  const u16* k1p = Kbase + (size_t)srow1 * DKH + skp1 * 8;
  const u16* v0p = Vbase + (size_t)srow0 * S_LEN + skp0 * 8;
  const u16* v1p = Vbase + (size_t)srow1 * S_LEN + skp1 * 8;

  // prologue stage tile 0 into buf 0
  gload16(&Ks[0][(w * 2) * 512], k0p);
  gload16(&Ks[0][(w * 2 + 1) * 512], k1p);
  gload16(&Vs[0][(w * 2) * 512], v0p);
  gload16(&Vs[0][(w * 2 + 1) * 512], v1p);

  bf16x8 qf[2][2];  // [qg][dk-half]
#pragma unroll
  for (int qg = 0; qg < 2; ++qg) {
    const u16* qp = Qb + ((size_t)bh * S_LEN + q0 + qh * 32 + qg * 16 + c) * DKH + g * 8;
    qf[qg][0] = *(const bf16x8*)qp;
    qf[qg][1] = *(const bf16x8*)(qp + 32);
  }
  f32x4 attT[4][2];  // [fd][qg]
#pragma unroll
  for (int i = 0; i < 4; ++i)
#pragma unroll
    for (int qg = 0; qg < 2; ++qg) attT[i][qg] = (f32x4){0.f, 0.f, 0.f, 0.f};
  float dacc[2] = {0.f, 0.f};
  const float L2E = 1.4426950408889634f;

  auto compute = [&](const u16* Kc, const u16* Vc) {
    f32x4 sT[2][2];  // [fm][qg]
    __builtin_amdgcn_s_setprio(1);
#pragma unroll
    for (int fm = 0; fm < 2; ++fm) {
      int row = h * 32 + fm * 16 + c;
      bf16x8 a0 = *(const bf16x8*)(Kc + row * 64 + ((g ^ (row & 7)) * 8));
      bf16x8 a1 = *(const bf16x8*)(Kc + row * 64 + (((4 + g) ^ (row & 7)) * 8));
#pragma unroll
      for (int qg = 0; qg < 2; ++qg) {
        f32x4 z = (f32x4){0.f, 0.f, 0.f, 0.f};
        z = __builtin_amdgcn_mfma_f32_16x16x32_bf16(a0, qf[qg][0], z, 0, 0, 0);
        sT[fm][qg] = __builtin_amdgcn_mfma_f32_16x16x32_bf16(a1, qf[qg][1], z, 0, 0, 0);
      }
    }
    __builtin_amdgcn_s_setprio(0);
    u32 wq[2][2][2];  // [qg][fm][r]
#pragma unroll
    for (int fm = 0; fm < 2; ++fm)
#pragma unroll
      for (int qg = 0; qg < 2; ++qg) {
        float pv[4];
#pragma unroll
        for (int j = 0; j < 4; ++j) {
          float cv = __builtin_amdgcn_cosf(sT[fm][qg][j]);  // revolutions
          float w2 = __fmaf_rn(cv, __fmaf_rn(0.2f * L2E, cv, L2E), -0.1f * L2E);
          pv[j] = __builtin_amdgcn_exp2f(w2);
        }
        dacc[qg] += (pv[0] + pv[1]) + (pv[2] + pv[3]);
        wq[qg][fm][0] = pk_bf16(pv[0], pv[1]);
        wq[qg][fm][1] = pk_bf16(pv[2], pv[3]);
      }
    bf16x8 pf[2];
#pragma unroll
    for (int qg = 0; qg < 2; ++qg) {
      u32 b0 = wq[qg][0][0], b2 = wq[qg][1][0];
      pl32swap(b0, b2);
      pl16swap(b0, b2);
      u32 b1 = wq[qg][0][1], b3 = wq[qg][1][1];
      pl32swap(b1, b3);
      pl16swap(b1, b3);
      pf[qg] = __builtin_bit_cast(bf16x8, (u32x4){b0, b1, b2, b3});
    }
    __builtin_amdgcn_s_setprio(1);
#pragma unroll
    for (int fd = 0; fd < 4; ++fd) {
      int vrow = fd * 16 + c;
      bf16x8 vf = *(const bf16x8*)(Vc + vrow * 64 + (((4 * h + g) ^ (vrow & 7)) * 8));
#pragma unroll
      for (int qg = 0; qg < 2; ++qg)
        attT[fd][qg] = __builtin_amdgcn_mfma_f32_16x16x32_bf16(vf, pf[qg], attT[fd][qg], 0, 0, 0);
    }
    __builtin_amdgcn_s_setprio(0);
  };

  const u16* kc0 = k0p;
  const u16* kc1 = k1p;
  const u16* vc0 = v0p;
  const u16* vc1 = v1p;
  __syncthreads();
  for (int kt = 0; kt < S_LEN; kt += 128) {
    // stage tile (kt+64) into buf1
    kc0 += 64 * DKH; kc1 += 64 * DKH; vc0 += 64; vc1 += 64;
    gload16(&Ks[1][(w * 2) * 512], kc0);
    gload16(&Ks[1][(w * 2 + 1) * 512], kc1);
    gload16(&Vs[1][(w * 2) * 512], vc0);
    gload16(&Vs[1][(w * 2 + 1) * 512], vc1);
    compute(Ks[0], Vs[0]);
    __syncthreads();
    if (kt + 128 < S_LEN) {  // stage tile (kt+128) into buf0
      kc0 += 64 * DKH; kc1 += 64 * DKH; vc0 += 64; vc1 += 64;
      gload16(&Ks[0][(w * 2) * 512], kc0);
      gload16(&Ks[0][(w * 2 + 1) * 512], kc1);
      gload16(&Vs[0][(w * 2) * 512], vc0);
      gload16(&Vs[0][(w * 2 + 1) * 512], vc1);
    }
    compute(Ks[1], Vs[1]);
    __syncthreads();
  }

  // ---- epilogue: reduce denominators + combine h-partners ----
#pragma unroll
  for (int qg = 0; qg < 2; ++qg) {
    dacc[qg] += __shfl_xor(dacc[qg], 16, 64);
    dacc[qg] += __shfl_xor(dacc[qg], 32, 64);
  }
  if (g == 0) {
    dred[w][0][c] = dacc[0];
    dred[w][1][c] = dacc[1];
  }
  float* R = (float*)&Ks[0][0];  // 32KB retired LDS; region per qh (8KB)
  if (h == 1) {
    float* Rq = R + qh * 2048;
#pragma unroll
    for (int fd = 0; fd < 4; ++fd)
#pragma unroll
      for (int qg = 0; qg < 2; ++qg)
        *(f32x4*)&Rq[(qg * 16 + c) * 64 + fd * 16 + 4 * g] = attT[fd][qg];
  }
  __syncthreads();
  if (h == 0) {
    float inv[2];
#pragma unroll
    for (int qg = 0; qg < 2; ++qg)
      inv[qg] = 1.f / (dred[w][qg][c] + dred[w ^ 2][qg][c]);
    float* Rq = R + qh * 2048;
#pragma unroll
    for (int fd = 0; fd < 4; ++fd)
#pragma unroll
      for (int qg = 0; qg < 2; ++qg) {
        f32x4 part = *(const f32x4*)&Rq[(qg * 16 + c) * 64 + fd * 16 + 4 * g];
        f32x4 tot = (attT[fd][qg] + part) * inv[qg];
        int q = q0 + qh * 32 + qg * 16 + c;
        *(f32x4*)(attbuf + ((size_t)bh * S_LEN + q) * DKH + fd * 16 + 4 * g) = tot;
      }
  }
}

// ---------------- head-reduce + a@Wo_eff + bias + residual + LayerNorm ----------------
__global__ __launch_bounds__(256) void fuse_out_ln_k(const float* __restrict__ attbuf,
    const float* __restrict__ Woeff, const float* __restrict__ bo,
    const float* __restrict__ x, const float* __restrict__ gamma,
    const float* __restrict__ beta, float* __restrict__ out) {
  __shared__ float red[8][256];
  __shared__ __align__(16) float a[8][64];
  __shared__ float sred[8][4][2];
  int t = threadIdx.x;
  int r0 = blockIdx.x * 8;
  int d = t & 63, hg = t >> 6;
#pragma unroll
  for (int rr = 0; rr < 8; ++rr) {
    int m = r0 + rr, b = m >> 11, sr = m & 2047;
    float pa = 0.f;
#pragma unroll
    for (int hh = 0; hh < 4; ++hh) {
      int h = hg * 4 + hh;
      pa += attbuf[(((size_t)(b * 16 + h)) * S_LEN + sr) * DKH + d];
    }
    red[rr][t] = pa;
  }
  __syncthreads();
#pragma unroll
  for (int e = 0; e < 2; ++e) {
    int idx = t + e * 256;
    int rr = idx >> 6, dd = idx & 63;
    a[rr][dd] = red[rr][dd] + red[rr][64 + dd] + red[rr][128 + dd] + red[rr][192 + dd];
  }
  __syncthreads();

  float o[8][4];
#pragma unroll
  for (int rr = 0; rr < 8; ++rr) { o[rr][0] = o[rr][1] = o[rr][2] = o[rr][3] = 0.f; }
  int c4 = t * 4;
  for (int dd = 0; dd < 64; dd += 4) {
    float4 wv0 = *(const float4*)(Woeff + (size_t)(dd + 0) * DMODEL + c4);
    float4 wv1 = *(const float4*)(Woeff + (size_t)(dd + 1) * DMODEL + c4);
    float4 wv2 = *(const float4*)(Woeff + (size_t)(dd + 2) * DMODEL + c4);
    float4 wv3 = *(const float4*)(Woeff + (size_t)(dd + 3) * DMODEL + c4);
#pragma unroll
    for (int rr = 0; rr < 8; ++rr) {
      float4 av = *(const float4*)&a[rr][dd];
      o[rr][0] += av.x * wv0.x + av.y * wv1.x + av.z * wv2.x + av.w * wv3.x;
      o[rr][1] += av.x * wv0.y + av.y * wv1.y + av.z * wv2.y + av.w * wv3.y;
      o[rr][2] += av.x * wv0.z + av.y * wv1.z + av.z * wv2.z + av.w * wv3.z;
      o[rr][3] += av.x * wv0.w + av.y * wv1.w + av.z * wv2.w + av.w * wv3.w;
    }
  }
  float4 bv = *(const float4*)(bo + c4);
  int w = t >> 6, lane = t & 63;
#pragma unroll
  for (int rr = 0; rr < 8; ++rr) {
    int m = r0 + rr;
    float4 xv = *(const float4*)(x + (size_t)m * DMODEL + c4);
    o[rr][0] += bv.x + xv.x;
    o[rr][1] += bv.y + xv.y;
    o[rr][2] += bv.z + xv.z;
    o[rr][3] += bv.w + xv.w;
    float s = o[rr][0] + o[rr][1] + o[rr][2] + o[rr][3];
    float q = o[rr][0] * o[rr][0] + o[rr][1] * o[rr][1] + o[rr][2] * o[rr][2] + o[rr][3] * o[rr][3];
#pragma unroll
    for (int mm = 1; mm < 64; mm <<= 1) {
      s += __shfl_xor(s, mm, 64);
      q += __shfl_xor(q, mm, 64);
    }
    if (lane == 0) { sred[rr][w][0] = s; sred[rr][w][1] = q; }
  }
  __syncthreads();
  float4 gv = *(const float4*)(gamma + c4);
  float4 bev = *(const float4*)(beta + c4);
#pragma unroll
  for (int rr = 0; rr < 8; ++rr) {
    float s = sred[rr][0][0] + sred[rr][1][0] + sred[rr][2][0] + sred[rr][3][0];
    float q = sred[rr][0][1] + sred[rr][1][1] + sred[rr][2][1] + sred[rr][3][1];
    float mu = s * (1.f / 1024.f);
    float var = q * (1.f / 1024.f) - mu * mu;
    float rs = rsqrtf(var + 1e-6f);
    int m = r0 + rr;
    float4 ov;
    ov.x = gv.x * (o[rr][0] - mu) * rs + bev.x;
    ov.y = gv.y * (o[rr][1] - mu) * rs + bev.y;
    ov.z = gv.z * (o[rr][2] - mu) * rs + bev.z;
    ov.w = gv.w * (o[rr][3] - mu) * rs + bev.w;
    *(float4*)(out + (size_t)m * DMODEL + c4) = ov;
  }
}

extern "C" void kernel_launch(void* const* d_in, const int* in_sizes, int n_in,
                              void* d_out, int out_size, void* d_ws, size_t ws_size,
                              hipStream_t stream) {
  const float* x = (const float*)d_in[0];
  const float* Wq = (const float*)d_in[1];
  const float* Wk = (const float*)d_in[2];
  const float* Wv = (const float*)d_in[3];
  const float* Wo = (const float*)d_in[4];
  const float* bo = (const float*)d_in[5];
  const float* ps = (const float*)d_in[6];
  const float* ent = (const float*)d_in[7];
  const float* gamma = (const float*)d_in[8];
  const float* beta = (const float*)d_in[9];
  float* out = (float*)d_out;

  char* ws = (char*)d_ws;
  size_t o = 0;
  u16* xb = (u16*)(ws + o);    o += (size_t)MROWS * DMODEL * 2;        // 8 MB
  u16* Wb = (u16*)(ws + o);    o += (size_t)3072 * 1024 * 2;           // 6 MB
  u16* Qb = (u16*)(ws + o);    o += (size_t)BH_CNT * S_LEN * DKH * 2;  // 8 MB
  u16* Kb = (u16*)(ws + o);    o += (size_t)BH_CNT * S_LEN * DKH * 2;  // 8 MB
  u16* Vt = (u16*)(ws + o);    o += (size_t)BH_CNT * S_LEN * DKH * 2;  // 8 MB
  float* Woeff = (float*)(ws + o);  o += (size_t)DKH * DMODEL * 4;     // 256 KB
  float* attbuf = (float*)(ws + o); o += (size_t)BH_CNT * S_LEN * DKH * 4;  // 16 MB

  prep_xb_k<<<dim3(4096), dim3(256), 0, stream>>>(x, xb);
  prep_w_k<<<dim3(32, 32, 3), dim3(32, 8), 0, stream>>>(Wq, Wk, Wv, ps, Wb);
  prep_woeff_k<<<dim3(256), dim3(256), 0, stream>>>(Wo, ent, Woeff);
  gemm_qkv_k<<<dim3(32, 24), dim3(256), 0, stream>>>(xb, Wb, Qb, Kb, Vt);
  attn_k<<<dim3(1024), dim3(256), 0, stream>>>(Qb, Kb, Vt, attbuf);
  fuse_out_ln_k<<<dim3(512), dim3(256), 0, stream>>>(attbuf, Woeff, bo, x, gamma, beta, out);
}

// Round 6
// 132.902 us; speedup vs baseline: 1.0787x; 1.0787x over previous
//
#include <hip/hip_runtime.h>
#include <cstdint>
#include <cstddef>

#define S_LEN 2048
#define DMODEL 1024
#define NHEADS 16
#define DKH 64
#define MROWS 4096
#define BH_CNT 32

typedef __bf16 bf16x8 __attribute__((ext_vector_type(8)));
typedef __bf16 bf16x2 __attribute__((ext_vector_type(2)));
typedef float f32x4 __attribute__((ext_vector_type(4)));
typedef unsigned int u32x4 __attribute__((ext_vector_type(4)));
typedef unsigned int u32;
typedef unsigned short u16;

__device__ __forceinline__ u16 f2bfu(float f) {
  u32 u = __float_as_uint(f);
  return (u16)((u + 0x7FFFu + ((u >> 16) & 1u)) >> 16);
}

// compiler-cast bf16 pack (lowers to v_cvt_pk_bf16_f32 on gfx950)
__device__ __forceinline__ u32 pk_bf16(float a, float b) {
  bf16x2 v;
  v[0] = (__bf16)a;
  v[1] = (__bf16)b;
  return __builtin_bit_cast(u32, v);
}

// true-swap cross-lane ops (gfx950): both operands modified
__device__ __forceinline__ void pl32swap(u32& a, u32& b) {
#if __has_builtin(__builtin_amdgcn_permlane32_swap)
  auto r = __builtin_amdgcn_permlane32_swap((int)a, (int)b, false, false);
  a = (u32)r[0]; b = (u32)r[1];
#else
  asm volatile("v_permlane32_swap_b32 %0, %1" : "+v"(a), "+v"(b));
#endif
}
__device__ __forceinline__ void pl16swap(u32& a, u32& b) {
#if __has_builtin(__builtin_amdgcn_permlane16_swap)
  auto r = __builtin_amdgcn_permlane16_swap((int)a, (int)b, false, false);
  a = (u32)r[0]; b = (u32)r[1];
#else
  asm volatile("v_permlane16_swap_b32 %0, %1" : "+v"(a), "+v"(b));
#endif
}

__device__ __forceinline__ void gload16(void* lds, const void* g) {
  __builtin_amdgcn_global_load_lds(
      (const __attribute__((address_space(1))) void*)g,
      (__attribute__((address_space(3))) void*)lds, 16, 0, 0);
}

// ---------------- prep: x -> bf16 ----------------
__global__ __launch_bounds__(256) void prep_xb_k(const float* __restrict__ x,
                                                 u16* __restrict__ xb) {
  int i = (blockIdx.x * 256 + threadIdx.x) * 4;
  float4 v = *(const float4*)(x + i);
  *(uint2*)(xb + i) = make_uint2(pk_bf16(v.x, v.y), pk_bf16(v.z, v.w));
}

// ---------------- prep: W^T (n-major) bf16, K pre-scaled ----------------
// K scale folds 1/sqrt(dk)*phase AND 1/(2pi): scores arrive in REVOLUTIONS.
__global__ __launch_bounds__(256) void prep_w_k(const float* __restrict__ Wq,
    const float* __restrict__ Wk, const float* __restrict__ Wv,
    const float* __restrict__ ps, u16* __restrict__ Wb) {
  __shared__ float tile[32][33];
  int sel = blockIdx.z;
  const float* W = sel == 0 ? Wq : (sel == 1 ? Wk : Wv);
  int k0 = blockIdx.x * 32, c0 = blockIdx.y * 32;
  int tx = threadIdx.x, ty = threadIdx.y;
#pragma unroll
  for (int i = 0; i < 4; ++i)
    tile[ty + i * 8][tx] = W[(size_t)(k0 + ty + i * 8) * DMODEL + c0 + tx];
  __syncthreads();
#pragma unroll
  for (int i = 0; i < 4; ++i) {
    int row = ty + i * 8;
    float v = tile[tx][row];
    if (sel == 1) v *= 0.019894367886486918f * ps[(c0 + row) >> 6];  // 0.125/(2pi)
    Wb[(size_t)(sel * 1024 + c0 + row) * DMODEL + k0 + tx] = f2bfu(v);
  }
}

// ---------------- prep: Wo_eff[d][j] = sum_m (sum_h ent[h][m]) * Wo[m*64+d][j] ----------------
__global__ __launch_bounds__(256) void prep_woeff_k(const float* __restrict__ Wo,
    const float* __restrict__ ent, float* __restrict__ Woeff) {
  __shared__ float e[16];
  int t = threadIdx.x;
  if (t < 16) {
    float s = 0.f;
#pragma unroll
    for (int h = 0; h < 16; ++h) s += ent[h * 16 + t];
    e[t] = s;
  }
  __syncthreads();
  int gid = blockIdx.x * 256 + t;
  int d = gid >> 10, j = gid & 1023;
  float acc = 0.f;
#pragma unroll
  for (int m = 0; m < 16; ++m) acc += e[m] * Wo[(size_t)((m << 6) + d) * DMODEL + j];
  Woeff[(size_t)d * DMODEL + j] = acc;
}

// ---------------- QKV projection GEMM: [4096,1024] x [1024,3072] ----------------
// 128x128 tile, BK=32, double-buffered staging, one barrier per K-step.
// Grid: XCD-rectangle swizzle (each XCD owns 8m x 12n tiles -> A 2MB + B 3MB
// stays L2-resident). Epilogue through LDS for coalesced stores.
__global__ __launch_bounds__(256) void gemm_qkv_k(const u16* __restrict__ xb,
    const u16* __restrict__ Wb, u16* __restrict__ Qb, u16* __restrict__ Kb,
    u16* __restrict__ Vt) {
  __shared__ __align__(16) u16 SMEM[2][2][128 * 32];  // [A/B][dbuf][tile]
  int bid = blockIdx.x;
  int xcd = bid & 7, wi = bid >> 3;
  int mg = xcd >> 1, ng = xcd & 1;
  int mt = mg * 8 + (wi & 7);
  int nt = ng * 12 + (wi >> 3);
  int m0 = mt * 128, n0 = nt * 128;
  int tid = threadIdx.x;
  int lane = tid & 63, w = tid >> 6;
  int c = lane & 15, g = lane >> 4;
  int wr = w >> 1, wc = w & 1;

  int cij0 = (w * 2) * 64 + lane, cij1 = (w * 2 + 1) * 64 + lane;
  int row0 = cij0 >> 2, kp0 = (cij0 & 3) ^ (row0 & 3);
  int row1 = cij1 >> 2, kp1 = (cij1 & 3) ^ (row1 & 3);
  const u16* a0p = xb + (size_t)(m0 + row0) * DMODEL + kp0 * 8;
  const u16* a1p = xb + (size_t)(m0 + row1) * DMODEL + kp1 * 8;
  const u16* b0p = Wb + (size_t)(n0 + row0) * DMODEL + kp0 * 8;
  const u16* b1p = Wb + (size_t)(n0 + row1) * DMODEL + kp1 * 8;

  f32x4 acc[4][4];
#pragma unroll
  for (int i = 0; i < 4; ++i)
#pragma unroll
    for (int j = 0; j < 4; ++j) acc[i][j] = (f32x4){0.f, 0.f, 0.f, 0.f};

  // prologue stage
  gload16(&SMEM[0][0][(w * 2) * 512], a0p);
  gload16(&SMEM[0][0][(w * 2 + 1) * 512], a1p);
  gload16(&SMEM[1][0][(w * 2) * 512], b0p);
  gload16(&SMEM[1][0][(w * 2 + 1) * 512], b1p);
  __syncthreads();

  int cur = 0;
  for (int kt = 0; kt < DMODEL; kt += 32) {
    if (kt + 32 < DMODEL) {
      int nx = cur ^ 1, ko = kt + 32;
      gload16(&SMEM[0][nx][(w * 2) * 512], a0p + ko);
      gload16(&SMEM[0][nx][(w * 2 + 1) * 512], a1p + ko);
      gload16(&SMEM[1][nx][(w * 2) * 512], b0p + ko);
      gload16(&SMEM[1][nx][(w * 2 + 1) * 512], b1p + ko);
    }
    const u16* Ac = SMEM[0][cur];
    const u16* Bc = SMEM[1][cur];
    bf16x8 af[4], bf[4];
#pragma unroll
    for (int i = 0; i < 4; ++i) {
      int ra = wr * 64 + i * 16 + c;
      af[i] = *(const bf16x8*)(Ac + ra * 32 + ((g ^ (ra & 3)) * 8));
      int rb = wc * 64 + i * 16 + c;
      bf[i] = *(const bf16x8*)(Bc + rb * 32 + ((g ^ (rb & 3)) * 8));
    }
#pragma unroll
    for (int i = 0; i < 4; ++i)
#pragma unroll
      for (int j = 0; j < 4; ++j)
        acc[i][j] = __builtin_amdgcn_mfma_f32_16x16x32_bf16(af[i], bf[j], acc[i][j], 0, 0, 0);
    __syncthreads();
    cur ^= 1;
  }

  // ---- epilogue via LDS (reuse staging buffers: 32KB = 128x128 u16) ----
  int sel = n0 >> 10;
  char* Ls = (char*)&SMEM[0][0][0];
  if (sel == 2) {
    // LDS layout transposed: row = n-local (d), col = m-local (s)
#pragma unroll
    for (int i = 0; i < 4; ++i)
#pragma unroll
      for (int jf = 0; jf < 4; ++jf) {
        int n = wc * 64 + jf * 16 + c;
        int m = wr * 64 + i * 16 + 4 * g;
        int byte = n * 256 + ((m * 2) ^ ((n & 7) << 4));
        *(uint2*)(Ls + byte) = make_uint2(pk_bf16(acc[i][jf][0], acc[i][jf][1]),
                                          pk_bf16(acc[i][jf][2], acc[i][jf][3]));
      }
  } else {
    // LDS layout: row = m-local (s), col = n-local (d)
#pragma unroll
    for (int i = 0; i < 4; ++i)
#pragma unroll
      for (int jf = 0; jf < 4; ++jf) {
        int n = wc * 64 + jf * 16 + c;
#pragma unroll
        for (int j = 0; j < 4; ++j) {
          int m = wr * 64 + i * 16 + 4 * g + j;
          int byte = m * 256 + ((n * 2) ^ ((m & 7) << 4));
          __bf16 hv = (__bf16)acc[i][jf][j];
          *(u16*)(Ls + byte) = __builtin_bit_cast(u16, hv);
        }
      }
  }
  __syncthreads();
  int r = tid >> 1, half = tid & 1;
  int h0 = (n0 & 1023) >> 6;
  int b = m0 >> 11, sbase = m0 & 2047;
  u16* dst;
  if (sel == 2) {
    int bh = b * 16 + h0 + (r >> 6), d = r & 63;
    dst = Vt + ((size_t)bh * DKH + d) * S_LEN + sbase + half * 64;
  } else {
    u16* base = (sel == 0 ? Qb : Kb);
    int bh = b * 16 + h0 + half;
    dst = base + ((size_t)bh * S_LEN + sbase + r) * DKH;
  }
#pragma unroll
  for (int kk = 0; kk < 8; ++kk) {
    int byte = r * 256 + ((half * 128 + kk * 16) ^ ((r & 7) << 4));
    *(uint4*)(dst + kk * 8) = *(const uint4*)(Ls + byte);
  }
}

// ---------------- fused cos-softmax flash attention ----------------
// 2x2 wave split (k-half x q-half). LUT softmax: P = f(frac(s)) via 2048-entry
// bf16 LDS table (f periodic) -> no transcendentals. Denominator via
// ones-row MFMA (sum_k P on the matrix pipe). permlane swaps redistribute
// P into the PV B-fragment (no LDS P round-trip). k-start rotated by qblk
// to decorrelate block barrier phases. XCD-swizzled grid.
__global__ __launch_bounds__(256, 4) void attn_k(const u16* __restrict__ Qb,
    const u16* __restrict__ Kb, const u16* __restrict__ Vt,
    float* __restrict__ attbuf) {
  __shared__ __align__(16) u16 Ks[2][64 * 64];
  __shared__ __align__(16) u16 Vs[2][64 * 64];
  __shared__ u16 Lut[2048];
  __shared__ float dred[4][2][16];
  int fid = blockIdx.x;
  int swz = (fid & 7) * 128 + (fid >> 3);  // 1024 blocks, 8 XCDs -> bijective
  int bh = swz >> 5, qblk = swz & 31;
  int tid = threadIdx.x;
  int lane = tid & 63, w = tid >> 6;
  int c = lane & 15, g = lane >> 4;
  int h = w >> 1, qh = w & 1;
  int q0 = qblk * 64;
  const float L2E = 1.4426950408889634f;

  // build LUT: f(t) = exp(cos(2pi t) + 0.1 cos(4pi t)), t = i/2048
#pragma unroll
  for (int e = 0; e < 8; ++e) {
    int i = tid + e * 256;
    float cv = __builtin_amdgcn_cosf((float)i * (1.f / 2048.f));
    float w2 = __fmaf_rn(cv, __fmaf_rn(0.2f * L2E, cv, L2E), -0.1f * L2E);
    __bf16 hv = (__bf16)__builtin_amdgcn_exp2f(w2);
    Lut[i] = __builtin_bit_cast(u16, hv);
  }

  const u16* Kbase = Kb + (size_t)bh * S_LEN * DKH;
  const u16* Vbase = Vt + (size_t)bh * DKH * S_LEN;
  int cij0 = (w * 2) * 64 + lane, cij1 = (w * 2 + 1) * 64 + lane;
  int srow0 = cij0 >> 3, skp0 = (cij0 & 7) ^ (srow0 & 7);
  int srow1 = cij1 >> 3, skp1 = (cij1 & 7) ^ (srow1 & 7);
  const u16* k0p = Kbase + (size_t)srow0 * DKH + skp0 * 8;
  const u16* k1p = Kbase + (size_t)srow1 * DKH + skp1 * 8;
  const u16* v0p = Vbase + (size_t)srow0 * S_LEN + skp0 * 8;
  const u16* v1p = Vbase + (size_t)srow1 * S_LEN + skp1 * 8;

  auto stage = [&](int buf, int tile) {
    gload16(&Ks[buf][(w * 2) * 512], k0p + (size_t)tile * 64 * DKH);
    gload16(&Ks[buf][(w * 2 + 1) * 512], k1p + (size_t)tile * 64 * DKH);
    gload16(&Vs[buf][(w * 2) * 512], v0p + tile * 64);
    gload16(&Vs[buf][(w * 2 + 1) * 512], v1p + tile * 64);
  };

  // prologue: stage rotated tile 0
  stage(0, qblk);

  bf16x8 qf[2][2];  // [qg][dk-half]
#pragma unroll
  for (int qg = 0; qg < 2; ++qg) {
    const u16* qp = Qb + ((size_t)bh * S_LEN + q0 + qh * 32 + qg * 16 + c) * DKH + g * 8;
    qf[qg][0] = *(const bf16x8*)qp;
    qf[qg][1] = *(const bf16x8*)(qp + 32);
  }
  bf16x8 onesf;
#pragma unroll
  for (int i = 0; i < 8; ++i) onesf[i] = (__bf16)1.0f;
  f32x4 attT[4][2];  // [fd][qg]
#pragma unroll
  for (int i = 0; i < 4; ++i)
#pragma unroll
    for (int qg = 0; qg < 2; ++qg) attT[i][qg] = (f32x4){0.f, 0.f, 0.f, 0.f};
  f32x4 denacc[2];
  denacc[0] = (f32x4){0.f, 0.f, 0.f, 0.f};
  denacc[1] = (f32x4){0.f, 0.f, 0.f, 0.f};

  auto compute = [&](const u16* Kc, const u16* Vc) {
    f32x4 sT[2][2];  // [fm][qg]
    __builtin_amdgcn_s_setprio(1);
#pragma unroll
    for (int fm = 0; fm < 2; ++fm) {
      int row = h * 32 + fm * 16 + c;
      bf16x8 a0 = *(const bf16x8*)(Kc + row * 64 + ((g ^ (row & 7)) * 8));
      bf16x8 a1 = *(const bf16x8*)(Kc + row * 64 + (((4 + g) ^ (row & 7)) * 8));
#pragma unroll
      for (int qg = 0; qg < 2; ++qg) {
        f32x4 z = (f32x4){0.f, 0.f, 0.f, 0.f};
        z = __builtin_amdgcn_mfma_f32_16x16x32_bf16(a0, qf[qg][0], z, 0, 0, 0);
        sT[fm][qg] = __builtin_amdgcn_mfma_f32_16x16x32_bf16(a1, qf[qg][1], z, 0, 0, 0);
      }
    }
    __builtin_amdgcn_s_setprio(0);
    u32 wq[2][2][2];  // [qg][fm][r]
#pragma unroll
    for (int fm = 0; fm < 2; ++fm)
#pragma unroll
      for (int qg = 0; qg < 2; ++qg) {
        u32 pb[4];
#pragma unroll
        for (int j = 0; j < 4; ++j) {
          float u = __builtin_amdgcn_fractf(sT[fm][qg][j]);
          int idx = (int)__fmaf_rn(u, 2048.f, 0.5f) & 2047;
          pb[j] = (u32)Lut[idx];
        }
        wq[qg][fm][0] = pb[0] | (pb[1] << 16);
        wq[qg][fm][1] = pb[2] | (pb[3] << 16);
      }
    bf16x8 pf[2];
#pragma unroll
    for (int qg = 0; qg < 2; ++qg) {
      u32 b0 = wq[qg][0][0], b2 = wq[qg][1][0];
      pl32swap(b0, b2);
      pl16swap(b0, b2);
      u32 b1 = wq[qg][0][1], b3 = wq[qg][1][1];
      pl32swap(b1, b3);
      pl16swap(b1, b3);
      pf[qg] = __builtin_bit_cast(bf16x8, (u32x4){b0, b1, b2, b3});
    }
    __builtin_amdgcn_s_setprio(1);
#pragma unroll
    for (int fd = 0; fd < 4; ++fd) {
      int vrow = fd * 16 + c;
      bf16x8 vf = *(const bf16x8*)(Vc + vrow * 64 + (((4 * h + g) ^ (vrow & 7)) * 8));
#pragma unroll
      for (int qg = 0; qg < 2; ++qg)
        attT[fd][qg] = __builtin_amdgcn_mfma_f32_16x16x32_bf16(vf, pf[qg], attT[fd][qg], 0, 0, 0);
    }
#pragma unroll
    for (int qg = 0; qg < 2; ++qg)
      denacc[qg] = __builtin_amdgcn_mfma_f32_16x16x32_bf16(onesf, pf[qg], denacc[qg], 0, 0, 0);
    __builtin_amdgcn_s_setprio(0);
  };

  __syncthreads();
  for (int t = 0; t < 32; t += 2) {
    stage(1, (t + 1 + qblk) & 31);
    compute(Ks[0], Vs[0]);
    __syncthreads();
    if (t + 2 < 32) stage(0, (t + 2 + qblk) & 31);
    compute(Ks[1], Vs[1]);
    __syncthreads();
  }

  // ---- epilogue: combine h-partners (denoms already complete per wave) ----
  if (g == 0) {
    dred[w][0][c] = denacc[0][0];
    dred[w][1][c] = denacc[1][0];
  }
  float* R = (float*)&Ks[0][0];  // 32KB retired LDS; region per qh (8KB)
  if (h == 1) {
    float* Rq = R + qh * 2048;
#pragma unroll
    for (int fd = 0; fd < 4; ++fd)
#pragma unroll
      for (int qg = 0; qg < 2; ++qg)
        *(f32x4*)&Rq[(qg * 16 + c) * 64 + fd * 16 + 4 * g] = attT[fd][qg];
  }
  __syncthreads();
  if (h == 0) {
    float inv[2];
#pragma unroll
    for (int qg = 0; qg < 2; ++qg)
      inv[qg] = 1.f / (dred[w][qg][c] + dred[w ^ 2][qg][c]);
    float* Rq = R + qh * 2048;
#pragma unroll
    for (int fd = 0; fd < 4; ++fd)
#pragma unroll
      for (int qg = 0; qg < 2; ++qg) {
        f32x4 part = *(const f32x4*)&Rq[(qg * 16 + c) * 64 + fd * 16 + 4 * g];
        f32x4 tot = (attT[fd][qg] + part) * inv[qg];
        int q = q0 + qh * 32 + qg * 16 + c;
        *(f32x4*)(attbuf + ((size_t)bh * S_LEN + q) * DKH + fd * 16 + 4 * g) = tot;
      }
  }
}

// ---------------- head-reduce + a@Wo_eff + bias + residual + LayerNorm ----------------
__global__ __launch_bounds__(256) void fuse_out_ln_k(const float* __restrict__ attbuf,
    const float* __restrict__ Woeff, const float* __restrict__ bo,
    const float* __restrict__ x, const float* __restrict__ gamma,
    const float* __restrict__ beta, float* __restrict__ out) {
  __shared__ float red[8][256];
  __shared__ __align__(16) float a[8][64];
  __shared__ float sred[8][4][2];
  int t = threadIdx.x;
  int r0 = blockIdx.x * 8;
  int d = t & 63, hg = t >> 6;
#pragma unroll
  for (int rr = 0; rr < 8; ++rr) {
    int m = r0 + rr, b = m >> 11, sr = m & 2047;
    float pa = 0.f;
#pragma unroll
    for (int hh = 0; hh < 4; ++hh) {
      int h = hg * 4 + hh;
      pa += attbuf[(((size_t)(b * 16 + h)) * S_LEN + sr) * DKH + d];
    }
    red[rr][t] = pa;
  }
  __syncthreads();
#pragma unroll
  for (int e = 0; e < 2; ++e) {
    int idx = t + e * 256;
    int rr = idx >> 6, dd = idx & 63;
    a[rr][dd] = red[rr][dd] + red[rr][64 + dd] + red[rr][128 + dd] + red[rr][192 + dd];
  }
  __syncthreads();

  float o[8][4];
#pragma unroll
  for (int rr = 0; rr < 8; ++rr) { o[rr][0] = o[rr][1] = o[rr][2] = o[rr][3] = 0.f; }
  int c4 = t * 4;
  for (int dd = 0; dd < 64; dd += 4) {
    float4 wv0 = *(const float4*)(Woeff + (size_t)(dd + 0) * DMODEL + c4);
    float4 wv1 = *(const float4*)(Woeff + (size_t)(dd + 1) * DMODEL + c4);
    float4 wv2 = *(const float4*)(Woeff + (size_t)(dd + 2) * DMODEL + c4);
    float4 wv3 = *(const float4*)(Woeff + (size_t)(dd + 3) * DMODEL + c4);
#pragma unroll
    for (int rr = 0; rr < 8; ++rr) {
      float4 av = *(const float4*)&a[rr][dd];
      o[rr][0] += av.x * wv0.x + av.y * wv1.x + av.z * wv2.x + av.w * wv3.x;
      o[rr][1] += av.x * wv0.y + av.y * wv1.y + av.z * wv2.y + av.w * wv3.y;
      o[rr][2] += av.x * wv0.z + av.y * wv1.z + av.z * wv2.z + av.w * wv3.z;
      o[rr][3] += av.x * wv0.w + av.y * wv1.w + av.z * wv2.w + av.w * wv3.w;
    }
  }
  float4 bv = *(const float4*)(bo + c4);
  int w = t >> 6, lane = t & 63;
#pragma unroll
  for (int rr = 0; rr < 8; ++rr) {
    int m = r0 + rr;
    float4 xv = *(const float4*)(x + (size_t)m * DMODEL + c4);
    o[rr][0] += bv.x + xv.x;
    o[rr][1] += bv.y + xv.y;
    o[rr][2] += bv.z + xv.z;
    o[rr][3] += bv.w + xv.w;
    float s = o[rr][0] + o[rr][1] + o[rr][2] + o[rr][3];
    float q = o[rr][0] * o[rr][0] + o[rr][1] * o[rr][1] + o[rr][2] * o[rr][2] + o[rr][3] * o[rr][3];
#pragma unroll
    for (int mm = 1; mm < 64; mm <<= 1) {
      s += __shfl_xor(s, mm, 64);
      q += __shfl_xor(q, mm, 64);
    }
    if (lane == 0) { sred[rr][w][0] = s; sred[rr][w][1] = q; }
  }
  __syncthreads();
  float4 gv = *(const float4*)(gamma + c4);
  float4 bev = *(const float4*)(beta + c4);
#pragma unroll
  for (int rr = 0; rr < 8; ++rr) {
    float s = sred[rr][0][0] + sred[rr][1][0] + sred[rr][2][0] + sred[rr][3][0];
    float q = sred[rr][0][1] + sred[rr][1][1] + sred[rr][2][1] + sred[rr][3][1];
    float mu = s * (1.f / 1024.f);
    float var = q * (1.f / 1024.f) - mu * mu;
    float rs = rsqrtf(var + 1e-6f);
    int m = r0 + rr;
    float4 ov;
    ov.x = gv.x * (o[rr][0] - mu) * rs + bev.x;
    ov.y = gv.y * (o[rr][1] - mu) * rs + bev.y;
    ov.z = gv.z * (o[rr][2] - mu) * rs + bev.z;
    ov.w = gv.w * (o[rr][3] - mu) * rs + bev.w;
    *(float4*)(out + (size_t)m * DMODEL + c4) = ov;
  }
}

extern "C" void kernel_launch(void* const* d_in, const int* in_sizes, int n_in,
                              void* d_out, int out_size, void* d_ws, size_t ws_size,
                              hipStream_t stream) {
  const float* x = (const float*)d_in[0];
  const float* Wq = (const float*)d_in[1];
  const float* Wk = (const float*)d_in[2];
  const float* Wv = (const float*)d_in[3];
  const float* Wo = (const float*)d_in[4];
  const float* bo = (const float*)d_in[5];
  const float* ps = (const float*)d_in[6];
  const float* ent = (const float*)d_in[7];
  const float* gamma = (const float*)d_in[8];
  const float* beta = (const float*)d_in[9];
  float* out = (float*)d_out;

  char* ws = (char*)d_ws;
  size_t o = 0;
  u16* xb = (u16*)(ws + o);    o += (size_t)MROWS * DMODEL * 2;        // 8 MB
  u16* Wb = (u16*)(ws + o);    o += (size_t)3072 * 1024 * 2;           // 6 MB
  u16* Qb = (u16*)(ws + o);    o += (size_t)BH_CNT * S_LEN * DKH * 2;  // 8 MB
  u16* Kb = (u16*)(ws + o);    o += (size_t)BH_CNT * S_LEN * DKH * 2;  // 8 MB
  u16* Vt = (u16*)(ws + o);    o += (size_t)BH_CNT * S_LEN * DKH * 2;  // 8 MB
  float* Woeff = (float*)(ws + o);  o += (size_t)DKH * DMODEL * 4;     // 256 KB
  float* attbuf = (float*)(ws + o); o += (size_t)BH_CNT * S_LEN * DKH * 4;  // 16 MB

  prep_xb_k<<<dim3(4096), dim3(256), 0, stream>>>(x, xb);
  prep_w_k<<<dim3(32, 32, 3), dim3(32, 8), 0, stream>>>(Wq, Wk, Wv, ps, Wb);
  prep_woeff_k<<<dim3(256), dim3(256), 0, stream>>>(Wo, ent, Woeff);
  gemm_qkv_k<<<dim3(768), dim3(256), 0, stream>>>(xb, Wb, Qb, Kb, Vt);
  attn_k<<<dim3(1024), dim3(256), 0, stream>>>(Qb, Kb, Vt, attbuf);
  fuse_out_ln_k<<<dim3(512), dim3(256), 0, stream>>>(attbuf, Woeff, bo, x, gamma, beta, out);
}

// Round 7
// 132.855 us; speedup vs baseline: 1.0791x; 1.0003x over previous
//
#include <hip/hip_runtime.h>
#include <cstdint>
#include <cstddef>

#define S_LEN 2048
#define DMODEL 1024
#define NHEADS 16
#define DKH 64
#define MROWS 4096
#define BH_CNT 32

typedef __bf16 bf16x8 __attribute__((ext_vector_type(8)));
typedef __bf16 bf16x2 __attribute__((ext_vector_type(2)));
typedef float f32x4 __attribute__((ext_vector_type(4)));
typedef unsigned int u32x4 __attribute__((ext_vector_type(4)));
typedef unsigned int u32;
typedef unsigned short u16;

__device__ __forceinline__ u16 f2bfu(float f) {
  u32 u = __float_as_uint(f);
  return (u16)((u + 0x7FFFu + ((u >> 16) & 1u)) >> 16);
}

// compiler-cast bf16 pack (lowers to v_cvt_pk_bf16_f32 on gfx950)
__device__ __forceinline__ u32 pk_bf16(float a, float b) {
  bf16x2 v;
  v[0] = (__bf16)a;
  v[1] = (__bf16)b;
  return __builtin_bit_cast(u32, v);
}

// true-swap cross-lane ops (gfx950): both operands modified
__device__ __forceinline__ void pl32swap(u32& a, u32& b) {
#if __has_builtin(__builtin_amdgcn_permlane32_swap)
  auto r = __builtin_amdgcn_permlane32_swap((int)a, (int)b, false, false);
  a = (u32)r[0]; b = (u32)r[1];
#else
  asm volatile("v_permlane32_swap_b32 %0, %1" : "+v"(a), "+v"(b));
#endif
}
__device__ __forceinline__ void pl16swap(u32& a, u32& b) {
#if __has_builtin(__builtin_amdgcn_permlane16_swap)
  auto r = __builtin_amdgcn_permlane16_swap((int)a, (int)b, false, false);
  a = (u32)r[0]; b = (u32)r[1];
#else
  asm volatile("v_permlane16_swap_b32 %0, %1" : "+v"(a), "+v"(b));
#endif
}

__device__ __forceinline__ void gload16(void* lds, const void* g) {
  __builtin_amdgcn_global_load_lds(
      (const __attribute__((address_space(1))) void*)g,
      (__attribute__((address_space(3))) void*)lds, 16, 0, 0);
}

// ---------------- prep: x -> bf16 ----------------
__global__ __launch_bounds__(256) void prep_xb_k(const float* __restrict__ x,
                                                 u16* __restrict__ xb) {
  int i = (blockIdx.x * 256 + threadIdx.x) * 4;
  float4 v = *(const float4*)(x + i);
  *(uint2*)(xb + i) = make_uint2(pk_bf16(v.x, v.y), pk_bf16(v.z, v.w));
}

// ---------------- prep: W^T (n-major) bf16, K pre-scaled ----------------
// K scale folds 1/sqrt(dk)*phase AND 1/(2pi): scores arrive in REVOLUTIONS.
__global__ __launch_bounds__(256) void prep_w_k(const float* __restrict__ Wq,
    const float* __restrict__ Wk, const float* __restrict__ Wv,
    const float* __restrict__ ps, u16* __restrict__ Wb) {
  __shared__ float tile[32][33];
  int sel = blockIdx.z;
  const float* W = sel == 0 ? Wq : (sel == 1 ? Wk : Wv);
  int k0 = blockIdx.x * 32, c0 = blockIdx.y * 32;
  int tx = threadIdx.x, ty = threadIdx.y;
#pragma unroll
  for (int i = 0; i < 4; ++i)
    tile[ty + i * 8][tx] = W[(size_t)(k0 + ty + i * 8) * DMODEL + c0 + tx];
  __syncthreads();
#pragma unroll
  for (int i = 0; i < 4; ++i) {
    int row = ty + i * 8;
    float v = tile[tx][row];
    if (sel == 1) v *= 0.019894367886486918f * ps[(c0 + row) >> 6];  // 0.125/(2pi)
    Wb[(size_t)(sel * 1024 + c0 + row) * DMODEL + k0 + tx] = f2bfu(v);
  }
}

// ---------------- prep: Wo_eff[d][j] = sum_m (sum_h ent[h][m]) * Wo[m*64+d][j] ----------------
__global__ __launch_bounds__(256) void prep_woeff_k(const float* __restrict__ Wo,
    const float* __restrict__ ent, float* __restrict__ Woeff) {
  __shared__ float e[16];
  int t = threadIdx.x;
  if (t < 16) {
    float s = 0.f;
#pragma unroll
    for (int h = 0; h < 16; ++h) s += ent[h * 16 + t];
    e[t] = s;
  }
  __syncthreads();
  int gid = blockIdx.x * 256 + t;
  int d = gid >> 10, j = gid & 1023;
  float acc = 0.f;
#pragma unroll
  for (int m = 0; m < 16; ++m) acc += e[m] * Wo[(size_t)((m << 6) + d) * DMODEL + j];
  Woeff[(size_t)d * DMODEL + j] = acc;
}

// ---------------- QKV projection GEMM: [4096,1024] x [1024,3072] ----------------
// 128x128 tile, BK=32, double-buffered staging, one barrier per K-step.
// Grid: XCD-rectangle swizzle. Epilogue through LDS for coalesced stores.
__global__ __launch_bounds__(256) void gemm_qkv_k(const u16* __restrict__ xb,
    const u16* __restrict__ Wb, u16* __restrict__ Qb, u16* __restrict__ Kb,
    u16* __restrict__ Vt) {
  __shared__ __align__(16) u16 SMEM[2][2][128 * 32];  // [A/B][dbuf][tile]
  int bid = blockIdx.x;
  int xcd = bid & 7, wi = bid >> 3;
  int mg = xcd >> 1, ng = xcd & 1;
  int mt = mg * 8 + (wi & 7);
  int nt = ng * 12 + (wi >> 3);
  int m0 = mt * 128, n0 = nt * 128;
  int tid = threadIdx.x;
  int lane = tid & 63, w = tid >> 6;
  int c = lane & 15, g = lane >> 4;
  int wr = w >> 1, wc = w & 1;

  int cij0 = (w * 2) * 64 + lane, cij1 = (w * 2 + 1) * 64 + lane;
  int row0 = cij0 >> 2, kp0 = (cij0 & 3) ^ (row0 & 3);
  int row1 = cij1 >> 2, kp1 = (cij1 & 3) ^ (row1 & 3);
  const u16* a0p = xb + (size_t)(m0 + row0) * DMODEL + kp0 * 8;
  const u16* a1p = xb + (size_t)(m0 + row1) * DMODEL + kp1 * 8;
  const u16* b0p = Wb + (size_t)(n0 + row0) * DMODEL + kp0 * 8;
  const u16* b1p = Wb + (size_t)(n0 + row1) * DMODEL + kp1 * 8;

  f32x4 acc[4][4];
#pragma unroll
  for (int i = 0; i < 4; ++i)
#pragma unroll
    for (int j = 0; j < 4; ++j) acc[i][j] = (f32x4){0.f, 0.f, 0.f, 0.f};

  // prologue stage
  gload16(&SMEM[0][0][(w * 2) * 512], a0p);
  gload16(&SMEM[0][0][(w * 2 + 1) * 512], a1p);
  gload16(&SMEM[1][0][(w * 2) * 512], b0p);
  gload16(&SMEM[1][0][(w * 2 + 1) * 512], b1p);
  __syncthreads();

  int cur = 0;
  for (int kt = 0; kt < DMODEL; kt += 32) {
    if (kt + 32 < DMODEL) {
      int nx = cur ^ 1, ko = kt + 32;
      gload16(&SMEM[0][nx][(w * 2) * 512], a0p + ko);
      gload16(&SMEM[0][nx][(w * 2 + 1) * 512], a1p + ko);
      gload16(&SMEM[1][nx][(w * 2) * 512], b0p + ko);
      gload16(&SMEM[1][nx][(w * 2 + 1) * 512], b1p + ko);
    }
    const u16* Ac = SMEM[0][cur];
    const u16* Bc = SMEM[1][cur];
    bf16x8 af[4], bf[4];
#pragma unroll
    for (int i = 0; i < 4; ++i) {
      int ra = wr * 64 + i * 16 + c;
      af[i] = *(const bf16x8*)(Ac + ra * 32 + ((g ^ (ra & 3)) * 8));
      int rb = wc * 64 + i * 16 + c;
      bf[i] = *(const bf16x8*)(Bc + rb * 32 + ((g ^ (rb & 3)) * 8));
    }
#pragma unroll
    for (int i = 0; i < 4; ++i)
#pragma unroll
      for (int j = 0; j < 4; ++j)
        acc[i][j] = __builtin_amdgcn_mfma_f32_16x16x32_bf16(af[i], bf[j], acc[i][j], 0, 0, 0);
    __syncthreads();
    cur ^= 1;
  }

  // ---- epilogue via LDS (reuse staging buffers: 32KB = 128x128 u16) ----
  int sel = n0 >> 10;
  char* Ls = (char*)&SMEM[0][0][0];
  if (sel == 2) {
    // LDS layout transposed: row = n-local (d), col = m-local (s)
#pragma unroll
    for (int i = 0; i < 4; ++i)
#pragma unroll
      for (int jf = 0; jf < 4; ++jf) {
        int n = wc * 64 + jf * 16 + c;
        int m = wr * 64 + i * 16 + 4 * g;
        int byte = n * 256 + ((m * 2) ^ ((n & 7) << 4));
        *(uint2*)(Ls + byte) = make_uint2(pk_bf16(acc[i][jf][0], acc[i][jf][1]),
                                          pk_bf16(acc[i][jf][2], acc[i][jf][3]));
      }
  } else {
    // LDS layout: row = m-local (s), col = n-local (d)
#pragma unroll
    for (int i = 0; i < 4; ++i)
#pragma unroll
      for (int jf = 0; jf < 4; ++jf) {
        int n = wc * 64 + jf * 16 + c;
#pragma unroll
        for (int j = 0; j < 4; ++j) {
          int m = wr * 64 + i * 16 + 4 * g + j;
          int byte = m * 256 + ((n * 2) ^ ((m & 7) << 4));
          __bf16 hv = (__bf16)acc[i][jf][j];
          *(u16*)(Ls + byte) = __builtin_bit_cast(u16, hv);
        }
      }
  }
  __syncthreads();
  int r = tid >> 1, half = tid & 1;
  int h0 = (n0 & 1023) >> 6;
  int b = m0 >> 11, sbase = m0 & 2047;
  u16* dst;
  if (sel == 2) {
    int bh = b * 16 + h0 + (r >> 6), d = r & 63;
    dst = Vt + ((size_t)bh * DKH + d) * S_LEN + sbase + half * 64;
  } else {
    u16* base = (sel == 0 ? Qb : Kb);
    int bh = b * 16 + h0 + half;
    dst = base + ((size_t)bh * S_LEN + sbase + r) * DKH;
  }
#pragma unroll
  for (int kk = 0; kk < 8; ++kk) {
    int byte = r * 256 + ((half * 128 + kk * 16) ^ ((r & 7) << 4));
    *(uint4*)(dst + kk * 8) = *(const uint4*)(Ls + byte);
  }
}

// ---------------- fused cos-softmax flash attention ----------------
// 2x2 wave split (k-half x q-half). In-register softmax: v_cos + 2 fma +
// v_exp2 per element (scores in revolutions; scale folded into K) -- no
// per-element LDS. Denominator via ones-row MFMA. permlane swaps move P
// into the PV B-fragment. ALL K/V LDS fragment addresses precomputed as
// lane pointers; double-buffer = compile-time +8192B immediate offset.
__global__ __launch_bounds__(256, 4) void attn_k(const u16* __restrict__ Qb,
    const u16* __restrict__ Kb, const u16* __restrict__ Vt,
    float* __restrict__ attbuf) {
  __shared__ __align__(16) u16 Ks[2][64 * 64];
  __shared__ __align__(16) u16 Vs[2][64 * 64];
  __shared__ float dred[4][2][16];
  int fid = blockIdx.x;
  int swz = (fid & 7) * 128 + (fid >> 3);  // 1024 blocks, 8 XCDs -> bijective
  int bh = swz >> 5, qblk = swz & 31;
  int tid = threadIdx.x;
  int lane = tid & 63, w = tid >> 6;
  int c = lane & 15, g = lane >> 4;
  int h = w >> 1, qh = w & 1;
  int q0 = qblk * 64;
  const float L2E = 1.4426950408889634f;

  const u16* Kbase = Kb + (size_t)bh * S_LEN * DKH;
  const u16* Vbase = Vt + (size_t)bh * DKH * S_LEN;
  int cij0 = (w * 2) * 64 + lane, cij1 = (w * 2 + 1) * 64 + lane;
  int srow0 = cij0 >> 3, skp0 = (cij0 & 7) ^ (srow0 & 7);
  int srow1 = cij1 >> 3, skp1 = (cij1 & 7) ^ (srow1 & 7);
  const u16* k0p = Kbase + (size_t)srow0 * DKH + skp0 * 8;
  const u16* k1p = Kbase + (size_t)srow1 * DKH + skp1 * 8;
  const u16* v0p = Vbase + (size_t)srow0 * S_LEN + skp0 * 8;
  const u16* v1p = Vbase + (size_t)srow1 * S_LEN + skp1 * 8;

  auto stage = [&](int buf, int tile) {
    gload16(&Ks[buf][(w * 2) * 512], k0p + (size_t)tile * 64 * DKH);
    gload16(&Ks[buf][(w * 2 + 1) * 512], k1p + (size_t)tile * 64 * DKH);
    gload16(&Vs[buf][(w * 2) * 512], v0p + tile * 64);
    gload16(&Vs[buf][(w * 2 + 1) * 512], v1p + tile * 64);
  };

  // prologue: stage rotated tile 0
  stage(0, qblk);

  bf16x8 qf[2][2];  // [qg][dk-half]
#pragma unroll
  for (int qg = 0; qg < 2; ++qg) {
    const u16* qp = Qb + ((size_t)bh * S_LEN + q0 + qh * 32 + qg * 16 + c) * DKH + g * 8;
    qf[qg][0] = *(const bf16x8*)qp;
    qf[qg][1] = *(const bf16x8*)(qp + 32);
  }
  bf16x8 onesf;
#pragma unroll
  for (int i = 0; i < 8; ++i) onesf[i] = (__bf16)1.0f;

  // precomputed LDS fragment pointers (buf0); buf1 = ptr + 4096 elems (8192B imm)
  const u16* kptr[2][2];  // [fm][dk-half]
#pragma unroll
  for (int fm = 0; fm < 2; ++fm) {
    int row = h * 32 + fm * 16 + c;
    kptr[fm][0] = &Ks[0][row * 64 + ((g ^ (row & 7)) * 8)];
    kptr[fm][1] = &Ks[0][row * 64 + (((4 + g) ^ (row & 7)) * 8)];
  }
  const u16* vptr[4];  // [fd]
#pragma unroll
  for (int fd = 0; fd < 4; ++fd) {
    int vrow = fd * 16 + c;
    vptr[fd] = &Vs[0][vrow * 64 + (((4 * h + g) ^ (vrow & 7)) * 8)];
  }

  f32x4 attT[4][2];  // [fd][qg]
#pragma unroll
  for (int i = 0; i < 4; ++i)
#pragma unroll
    for (int qg = 0; qg < 2; ++qg) attT[i][qg] = (f32x4){0.f, 0.f, 0.f, 0.f};
  f32x4 denacc[2];
  denacc[0] = (f32x4){0.f, 0.f, 0.f, 0.f};
  denacc[1] = (f32x4){0.f, 0.f, 0.f, 0.f};

  auto compute = [&](int BUF) {  // BUF is a compile-time literal at each call
    const int off = BUF * 4096;
    f32x4 sT[2][2];  // [fm][qg]
    __builtin_amdgcn_s_setprio(1);
#pragma unroll
    for (int fm = 0; fm < 2; ++fm) {
      bf16x8 a0 = *(const bf16x8*)(kptr[fm][0] + off);
      bf16x8 a1 = *(const bf16x8*)(kptr[fm][1] + off);
#pragma unroll
      for (int qg = 0; qg < 2; ++qg) {
        f32x4 z = (f32x4){0.f, 0.f, 0.f, 0.f};
        z = __builtin_amdgcn_mfma_f32_16x16x32_bf16(a0, qf[qg][0], z, 0, 0, 0);
        sT[fm][qg] = __builtin_amdgcn_mfma_f32_16x16x32_bf16(a1, qf[qg][1], z, 0, 0, 0);
      }
    }
    __builtin_amdgcn_s_setprio(0);
    u32 wq[2][2][2];  // [qg][fm][r]
#pragma unroll
    for (int fm = 0; fm < 2; ++fm)
#pragma unroll
      for (int qg = 0; qg < 2; ++qg) {
        float pv[4];
#pragma unroll
        for (int j = 0; j < 4; ++j) {
          float cv = __builtin_amdgcn_cosf(sT[fm][qg][j]);  // revolutions
          float w2 = __fmaf_rn(cv, __fmaf_rn(0.2f * L2E, cv, L2E), -0.1f * L2E);
          pv[j] = __builtin_amdgcn_exp2f(w2);
        }
        wq[qg][fm][0] = pk_bf16(pv[0], pv[1]);
        wq[qg][fm][1] = pk_bf16(pv[2], pv[3]);
      }
    bf16x8 pf[2];
#pragma unroll
    for (int qg = 0; qg < 2; ++qg) {
      u32 b0 = wq[qg][0][0], b2 = wq[qg][1][0];
      pl32swap(b0, b2);
      pl16swap(b0, b2);
      u32 b1 = wq[qg][0][1], b3 = wq[qg][1][1];
      pl32swap(b1, b3);
      pl16swap(b1, b3);
      pf[qg] = __builtin_bit_cast(bf16x8, (u32x4){b0, b1, b2, b3});
    }
    __builtin_amdgcn_s_setprio(1);
#pragma unroll
    for (int fd = 0; fd < 4; ++fd) {
      bf16x8 vf = *(const bf16x8*)(vptr[fd] + off);
#pragma unroll
      for (int qg = 0; qg < 2; ++qg)
        attT[fd][qg] = __builtin_amdgcn_mfma_f32_16x16x32_bf16(vf, pf[qg], attT[fd][qg], 0, 0, 0);
    }
#pragma unroll
    for (int qg = 0; qg < 2; ++qg)
      denacc[qg] = __builtin_amdgcn_mfma_f32_16x16x32_bf16(onesf, pf[qg], denacc[qg], 0, 0, 0);
    __builtin_amdgcn_s_setprio(0);
  };

  __syncthreads();
  for (int t = 0; t < 32; t += 2) {
    stage(1, (t + 1 + qblk) & 31);
    compute(0);
    __syncthreads();
    if (t + 2 < 32) stage(0, (t + 2 + qblk) & 31);
    compute(1);
    __syncthreads();
  }

  // ---- epilogue: combine h-partners (denoms already complete per wave) ----
  if (g == 0) {
    dred[w][0][c] = denacc[0][0];
    dred[w][1][c] = denacc[1][0];
  }
  float* R = (float*)&Ks[0][0];  // 32KB retired LDS; region per qh (8KB)
  if (h == 1) {
    float* Rq = R + qh * 2048;
#pragma unroll
    for (int fd = 0; fd < 4; ++fd)
#pragma unroll
      for (int qg = 0; qg < 2; ++qg)
        *(f32x4*)&Rq[(qg * 16 + c) * 64 + fd * 16 + 4 * g] = attT[fd][qg];
  }
  __syncthreads();
  if (h == 0) {
    float inv[2];
#pragma unroll
    for (int qg = 0; qg < 2; ++qg)
      inv[qg] = 1.f / (dred[w][qg][c] + dred[w ^ 2][qg][c]);
    float* Rq = R + qh * 2048;
#pragma unroll
    for (int fd = 0; fd < 4; ++fd)
#pragma unroll
      for (int qg = 0; qg < 2; ++qg) {
        f32x4 part = *(const f32x4*)&Rq[(qg * 16 + c) * 64 + fd * 16 + 4 * g];
        f32x4 tot = (attT[fd][qg] + part) * inv[qg];
        int q = q0 + qh * 32 + qg * 16 + c;
        *(f32x4*)(attbuf + ((size_t)bh * S_LEN + q) * DKH + fd * 16 + 4 * g) = tot;
      }
  }
}

// ---------------- head-reduce + a@Wo_eff + bias + residual + LayerNorm ----------------
__global__ __launch_bounds__(256) void fuse_out_ln_k(const float* __restrict__ attbuf,
    const float* __restrict__ Woeff, const float* __restrict__ bo,
    const float* __restrict__ x, const float* __restrict__ gamma,
    const float* __restrict__ beta, float* __restrict__ out) {
  __shared__ float red[8][256];
  __shared__ __align__(16) float a[8][64];
  __shared__ float sred[8][4][2];
  int t = threadIdx.x;
  int r0 = blockIdx.x * 8;
  int d = t & 63, hg = t >> 6;
#pragma unroll
  for (int rr = 0; rr < 8; ++rr) {
    int m = r0 + rr, b = m >> 11, sr = m & 2047;
    float pa = 0.f;
#pragma unroll
    for (int hh = 0; hh < 4; ++hh) {
      int h = hg * 4 + hh;
      pa += attbuf[(((size_t)(b * 16 + h)) * S_LEN + sr) * DKH + d];
    }
    red[rr][t] = pa;
  }
  __syncthreads();
#pragma unroll
  for (int e = 0; e < 2; ++e) {
    int idx = t + e * 256;
    int rr = idx >> 6, dd = idx & 63;
    a[rr][dd] = red[rr][dd] + red[rr][64 + dd] + red[rr][128 + dd] + red[rr][192 + dd];
  }
  __syncthreads();

  float o[8][4];
#pragma unroll
  for (int rr = 0; rr < 8; ++rr) { o[rr][0] = o[rr][1] = o[rr][2] = o[rr][3] = 0.f; }
  int c4 = t * 4;
  for (int dd = 0; dd < 64; dd += 4) {
    float4 wv0 = *(const float4*)(Woeff + (size_t)(dd + 0) * DMODEL + c4);
    float4 wv1 = *(const float4*)(Woeff + (size_t)(dd + 1) * DMODEL + c4);
    float4 wv2 = *(const float4*)(Woeff + (size_t)(dd + 2) * DMODEL + c4);
    float4 wv3 = *(const float4*)(Woeff + (size_t)(dd + 3) * DMODEL + c4);
#pragma unroll
    for (int rr = 0; rr < 8; ++rr) {
      float4 av = *(const float4*)&a[rr][dd];
      o[rr][0] += av.x * wv0.x + av.y * wv1.x + av.z * wv2.x + av.w * wv3.x;
      o[rr][1] += av.x * wv0.y + av.y * wv1.y + av.z * wv2.y + av.w * wv3.y;
      o[rr][2] += av.x * wv0.z + av.y * wv1.z + av.z * wv2.z + av.w * wv3.z;
      o[rr][3] += av.x * wv0.w + av.y * wv1.w + av.z * wv2.w + av.w * wv3.w;
    }
  }
  float4 bv = *(const float4*)(bo + c4);
  int w = t >> 6, lane = t & 63;
#pragma unroll
  for (int rr = 0; rr < 8; ++rr) {
    int m = r0 + rr;
    float4 xv = *(const float4*)(x + (size_t)m * DMODEL + c4);
    o[rr][0] += bv.x + xv.x;
    o[rr][1] += bv.y + xv.y;
    o[rr][2] += bv.z + xv.z;
    o[rr][3] += bv.w + xv.w;
    float s = o[rr][0] + o[rr][1] + o[rr][2] + o[rr][3];
    float q = o[rr][0] * o[rr][0] + o[rr][1] * o[rr][1] + o[rr][2] * o[rr][2] + o[rr][3] * o[rr][3];
#pragma unroll
    for (int mm = 1; mm < 64; mm <<= 1) {
      s += __shfl_xor(s, mm, 64);
      q += __shfl_xor(q, mm, 64);
    }
    if (lane == 0) { sred[rr][w][0] = s; sred[rr][w][1] = q; }
  }
  __syncthreads();
  float4 gv = *(const float4*)(gamma + c4);
  float4 bev = *(const float4*)(beta + c4);
#pragma unroll
  for (int rr = 0; rr < 8; ++rr) {
    float s = sred[rr][0][0] + sred[rr][1][0] + sred[rr][2][0] + sred[rr][3][0];
    float q = sred[rr][0][1] + sred[rr][1][1] + sred[rr][2][1] + sred[rr][3][1];
    float mu = s * (1.f / 1024.f);
    float var = q * (1.f / 1024.f) - mu * mu;
    float rs = rsqrtf(var + 1e-6f);
    int m = r0 + rr;
    float4 ov;
    ov.x = gv.x * (o[rr][0] - mu) * rs + bev.x;
    ov.y = gv.y * (o[rr][1] - mu) * rs + bev.y;
    ov.z = gv.z * (o[rr][2] - mu) * rs + bev.z;
    ov.w = gv.w * (o[rr][3] - mu) * rs + bev.w;
    *(float4*)(out + (size_t)m * DMODEL + c4) = ov;
  }
}

extern "C" void kernel_launch(void* const* d_in, const int* in_sizes, int n_in,
                              void* d_out, int out_size, void* d_ws, size_t ws_size,
                              hipStream_t stream) {
  const float* x = (const float*)d_in[0];
  const float* Wq = (const float*)d_in[1];
  const float* Wk = (const float*)d_in[2];
  const float* Wv = (const float*)d_in[3];
  const float* Wo = (const float*)d_in[4];
  const float* bo = (const float*)d_in[5];
  const float* ps = (const float*)d_in[6];
  const float* ent = (const float*)d_in[7];
  const float* gamma = (const float*)d_in[8];
  const float* beta = (const float*)d_in[9];
  float* out = (float*)d_out;

  char* ws = (char*)d_ws;
  size_t o = 0;
  u16* xb = (u16*)(ws + o);    o += (size_t)MROWS * DMODEL * 2;        // 8 MB
  u16* Wb = (u16*)(ws + o);    o += (size_t)3072 * 1024 * 2;           // 6 MB
  u16* Qb = (u16*)(ws + o);    o += (size_t)BH_CNT * S_LEN * DKH * 2;  // 8 MB
  u16* Kb = (u16*)(ws + o);    o += (size_t)BH_CNT * S_LEN * DKH * 2;  // 8 MB
  u16* Vt = (u16*)(ws + o);    o += (size_t)BH_CNT * S_LEN * DKH * 2;  // 8 MB
  float* Woeff = (float*)(ws + o);  o += (size_t)DKH * DMODEL * 4;     // 256 KB
  float* attbuf = (float*)(ws + o); o += (size_t)BH_CNT * S_LEN * DKH * 4;  // 16 MB

  prep_xb_k<<<dim3(4096), dim3(256), 0, stream>>>(x, xb);
  prep_w_k<<<dim3(32, 32, 3), dim3(32, 8), 0, stream>>>(Wq, Wk, Wv, ps, Wb);
  prep_woeff_k<<<dim3(256), dim3(256), 0, stream>>>(Wo, ent, Woeff);
  gemm_qkv_k<<<dim3(768), dim3(256), 0, stream>>>(xb, Wb, Qb, Kb, Vt);
  attn_k<<<dim3(1024), dim3(256), 0, stream>>>(Qb, Kb, Vt, attbuf);
  fuse_out_ln_k<<<dim3(512), dim3(256), 0, stream>>>(attbuf, Woeff, bo, x, gamma, beta, out);
}